// Round 9
// baseline (370.113 us; speedup 1.0000x reference)
//
#include <hip/hip_runtime.h>
#include <cstdint>

#define NSTEP 1000
#define NELEM 45056          // 16 * 2816 = 1024 * 44
#define HW    2816           // 64 * 44
#define EPB   44             // elements per block -> grid = 1024 = 4 blocks/CU exactly
#define PW    7              // producer waves per block
#define BLK   ((PW + 1) * 64)// 512 threads: 7 producer waves + 1 consumer wave
#define WIN   40             // k-steps per window; NSTEP % WIN == 0
#define NWIN  (NSTEP / WIN)  // 25
#define NBUF  2              // windows in flight (double buffer)
#define CELLS (WIN * EPB)    // 1760 (k,e) cells per window
#define TABC_OFF 16384       // byte offset of tabC in workspace
#define WS_NEED  (TABC_OFF + NSTEP * 8)

// ---------- compile-time fp64 DDIM schedule (bit-exact vs np.linspace+cumprod) ----------
struct AlphTab { float a[NSTEP + 1]; };

constexpr AlphTab make_alph() {
    AlphTab t{};
    t.a[0] = 1.0f;
    double alph = 1.0;
    const double start = 1e-4, stop = 0.02;
    const double step = (stop - start) / 999.0;
    for (int i = 0; i < NSTEP; ++i) {
        double beta = (i == NSTEP - 1) ? stop : ((double)i * step + start);
        alph *= (1.0 - beta);
        t.a[i + 1] = (float)alph;
    }
    return t;
}
constexpr AlphTab ALPH = make_alph();

// ---------- Threefry-2x32-20 (partitionable-mode usage: ctr=(0,j), out = x0^x1) ----------
__device__ __forceinline__ void tf20(uint32_t K0, uint32_t K1, uint32_t K2,
                                     uint32_t& x0, uint32_t& x1) {
    x0 += K0; x1 += K1;
#define TFR(r) { x0 += x1; x1 = ((x1 << r) | (x1 >> (32 - r))); x1 ^= x0; }
    TFR(13) TFR(15) TFR(26) TFR(6)
    x0 += K1; x1 += K2 + 1u;
    TFR(17) TFR(29) TFR(16) TFR(24)
    x0 += K2; x1 += K0 + 2u;
    TFR(13) TFR(15) TFR(26) TFR(6)
    x0 += K0; x1 += K1 + 3u;
    TFR(17) TFR(29) TFR(16) TFR(24)
    x0 += K1; x1 += K2 + 4u;
    TFR(13) TFR(15) TFR(26) TFR(6)
    x0 += K2; x1 += K0 + 5u;
#undef TFR
}

__device__ __forceinline__ float fast_tanh(float x) {
    const float e2 = __expf(x + x);
    const float r  = __builtin_amdgcn_rcpf(e2 + 1.0f);
    return fmaf(-2.0f, r, 1.0f);
}

// bits -> erfinv(u). Dual-poly, single select; wave-uniform skip of the far
// branch (P(any of 64 lanes far) ~ 19%). Bit-identical to the reference poly.
__device__ __forceinline__ float bits_to_erfinv(uint32_t bits) {
    const float f2 = __uint_as_float((bits >> 9) | 0x3F800000u) - 1.0f;
    const float u  = f2 * 2.0f - 0.99999994f;
    const float t1 = (1.0f - u) * (1.0f + u);
    const float w  = __log2f(t1) * -0.6931472f;
    const bool  lt = w < 5.0f;

    const float wwn = w - 2.5f;
    float pn =           2.81022636e-08f;
    pn = fmaf(pn, wwn,   3.43273939e-07f);
    pn = fmaf(pn, wwn,  -3.5233877e-06f);
    pn = fmaf(pn, wwn,  -4.39150654e-06f);
    pn = fmaf(pn, wwn,   0.00021858087f);
    pn = fmaf(pn, wwn,  -0.00125372503f);
    pn = fmaf(pn, wwn,  -0.00417768164f);
    pn = fmaf(pn, wwn,   0.246640727f);
    pn = fmaf(pn, wwn,   1.50140941f);

    float p = pn;
    if (__any(!lt)) {                                 // wave-uniform branch
        const float sw  = __builtin_amdgcn_sqrtf(w);  // w >= 0 always
        const float wwf = sw - 3.0f;
        float pf =           -0.000200214257f;
        pf = fmaf(pf, wwf,    0.000100950558f);
        pf = fmaf(pf, wwf,    0.00134934322f);
        pf = fmaf(pf, wwf,   -0.00367342844f);
        pf = fmaf(pf, wwf,    0.00573950773f);
        pf = fmaf(pf, wwf,   -0.0076224613f);
        pf = fmaf(pf, wwf,    0.00943887047f);
        pf = fmaf(pf, wwf,    1.00167406f);
        pf = fmaf(pf, wwf,    2.83297682f);
        p = lt ? pn : pf;
    }
    return p * u;
}

// =====================================================================
// Setup kernel: DDIM schedule + per-step threefry keys -> GLOBAL memory.
// =====================================================================
__global__ __launch_bounds__(256)
void setup_kernel(const float* __restrict__ tsc_p,
                  uint4* __restrict__ tabPg, uint2* __restrict__ tabCg) {
    const int k = (int)(blockIdx.x * 256u + threadIdx.x);
    if (k >= NSTEP) return;
    const float tsc = tsc_p[0];
    const float L2E2 = 2.8853900817779268f;      // 2*log2(e)
    const int t = 999 - k;
    const float at  = ALPH.a[t + 1];
    const float atn = ALPH.a[t];
    const float c1 = 0.1f * sqrtf((1.0f - at / atn) * (1.0f - atn) / (1.0f - at));
    const float c2 = sqrtf(fmaxf(1.0f - atn - c1 * c1, 0.0f));
    const float rs = 1.0f / sqrtf(1.0f - at);
    const float A  = sqrtf(atn) - c2 * sqrtf(at) * rs;
    const float e  = c2 * rs;
    const float temb = tsc * ((float)t / 1000.0f);
    // fold_in(key(42), t): key <- threefry(key=[0,42], ctr=[0,t])
    uint32_t k0 = 0u, k1 = (uint32_t)t;
    tf20(0u, 42u, 0x1BD11BDAu ^ 42u, k0, k1);
    tabPg[k] = make_uint4(__float_as_uint(c1 * 1.4142135f),
                          __float_as_uint(e), k0, k1);
    tabCg[k] = make_uint2(__float_as_uint(A), __float_as_uint(temb * L2E2));
}

// =====================================================================
// Fused producer-consumer kernel, EXACT-OCCUPANCY layout.
//   grid = NELEM/EPB = 1024 blocks x 512 threads (8 waves)
//        = 4 blocks/CU on EVERY CU = 32 waves/CU (hardware cap), zero
//          grid imbalance (r8's 704-over-256 cost 8-9%).
//   waves 0..6 (producers): flattened (k,e) cell space, ALL 64 lanes
//     always full; cell c -> k = c/44 (magic umulhi), e = c - 44k.
//     Per-cell table read is a per-lane L1-broadcast global_load_dwordx4.
//   wave 7 (consumer): serial DDIM scan, 44 active lanes, LDS -> out.
// LDS: dbuf 2x1760 + sT 44 floats ~ 14.3 KB -> 4 blocks/CU.
// One __syncthreads per window (NBUF=2 double-buffer invariant).
// =====================================================================
__global__ __launch_bounds__(BLK, 8)
void fused_kernel(const float* __restrict__ skes,
                  const float* __restrict__ silT,
                  const float* __restrict__ wskes,
                  const float* __restrict__ wsil_p,
                  const uint4* __restrict__ tabPg,
                  const uint2* __restrict__ tabCg,
                  float* __restrict__ out) {
    __shared__ __align__(16) float dbuf[NBUF][CELLS];
    __shared__ float lds_sT[EPB];

    const int wid  = (int)(threadIdx.x >> 6);
    const int lane = (int)(threadIdx.x & 63);
    const int j0   = (int)(blockIdx.x * EPB);

    if (threadIdx.x < EPB) lds_sT[threadIdx.x] = silT[j0 + threadIdx.x];

    // consumer-only per-lane state (lanes >= EPB mirror lane EPB-1, store-guarded)
    const int le = (lane < EPB) ? lane : (EPB - 1);
    float cc2 = 0.0f, ws2 = 0.0f, sil = 0.0f;
    if (wid == PW) {
        const float L2E2 = 2.8853900817779268f;
        const int j  = j0 + le;
        const int ns = j / HW;
        const int hw = j - ns * HW;
        const int n  = ns >> 3;
        const int ss = ns & 7;
        const float* sk = skes + (size_t)((n * 3) * 8 + ss) * HW + hw;
        const float w0 = wskes[0], w1 = wskes[1], w2 = wskes[2];
        const float cond = fmaf(w2, sk[2 * 8 * HW], fmaf(w1, sk[8 * HW], w0 * sk[0]));
        cc2 = cond * L2E2;
        ws2 = wsil_p[0] * L2E2;
        sil = silT[j];
    }

    __syncthreads();   // lds_sT ready

    // ---- producer helper is inlined twice (prologue + steady state) ----
#define PRODUCE_WINDOW(wdst)                                                   \
    do {                                                                       \
        const int kbase = (wdst) * WIN;                                        \
        float* db = &dbuf[(wdst) & (NBUF - 1)][0];                             \
        _Pragma("unroll 2")                                                    \
        for (int c = wid * 64 + lane; c < CELLS; c += PW * 64) {               \
            const int k = (int)__umulhi((unsigned)c, 97612894u); /* c/44 */    \
            const int e = c - k * 44;                                          \
            const uint4 ta = tabPg[kbase + k];                                 \
            const float sTe = lds_sT[e];                                       \
            uint32_t x0 = 0u, x1 = (uint32_t)(j0 + e);                         \
            tf20(ta.z, ta.w, ta.z ^ ta.w ^ 0x1BD11BDAu, x0, x1);               \
            const float ei = bits_to_erfinv(x0 ^ x1);                          \
            db[c] = fmaf(__uint_as_float(ta.x), ei,                            \
                         __uint_as_float(ta.y) * sTe);                         \
        }                                                                      \
    } while (0)

    if (wid < PW) {
        PRODUCE_WINDOW(0);
    }
    __syncthreads();   // window 0 ready

    float* op = out + j0 + lane;

    for (int w = 0; w < NWIN; ++w) {
        if (wid < PW) {
            if (w + 1 < NWIN) {
                PRODUCE_WINDOW(w + 1);
            }
        } else {
            // ---- consumer: serial scan over window w (44 active lanes) ----
            const float* db = &dbuf[w & (NBUF - 1)][0];
            const int kb = w * WIN;
#pragma unroll 1
            for (int g = 0; g < WIN / 8; ++g) {
                float d8[8]; uint2 t8[8];
#pragma unroll
                for (int i = 0; i < 8; ++i) {
                    d8[i] = db[(g * 8 + i) * EPB + le];
                    t8[i] = tabCg[kb + g * 8 + i];     // uniform -> s_load
                }
#pragma unroll
                for (int i = 0; i < 8; ++i) {
                    const float A  = __uint_as_float(t8[i].x);
                    const float tb = __uint_as_float(t8[i].y);
                    const float e2 = __builtin_amdgcn_exp2f(fmaf(ws2, sil, cc2 + tb));
                    const float r  = __builtin_amdgcn_rcpf(e2 + 1.0f);
                    const float s0 = fmaf(-2.0f, r, 1.0f);
                    if (lane < EPB) *op = s0;
                    op += NELEM;
                    sil = fmaf(A, s0, d8[i]);
                }
            }
        }
        __syncthreads();   // window w consumed / window w+1 ready
    }
#undef PRODUCE_WINDOW
}

// =====================================================================
// Fallback: monolithic kernel (only if ws_size too small). r0 semantics.
// =====================================================================
__global__ __launch_bounds__(256)
void diffgait_mono(const float* __restrict__ skes,
                   const float* __restrict__ silT,
                   const float* __restrict__ wskes,
                   const float* __restrict__ wsil_p,
                   const float* __restrict__ tsc_p,
                   float* __restrict__ out) {
    __shared__ __align__(16) uint32_t tab[NSTEP][8];
    const float wsil = wsil_p[0];
    const float tsc  = tsc_p[0];
    for (int k = (int)threadIdx.x; k < NSTEP; k += 256) {
        const int t = 999 - k;
        const float at  = ALPH.a[t + 1];
        const float atn = ALPH.a[t];
        const float c1 = 0.1f * sqrtf((1.0f - at / atn) * (1.0f - atn) / (1.0f - at));
        const float c2 = sqrtf(fmaxf(1.0f - atn - c1 * c1, 0.0f));
        const float rs = 1.0f / sqrtf(1.0f - at);
        const float A  = sqrtf(atn) - c2 * sqrtf(at) * rs;
        const float e  = c2 * rs;
        const float temb = tsc * ((float)t / 1000.0f);
        uint32_t x0 = 0u, x1 = (uint32_t)t;
        tf20(0u, 42u, 0x1BD11BDAu ^ 42u, x0, x1);
        tab[k][0] = __float_as_uint(A);
        tab[k][1] = __float_as_uint(temb);
        tab[k][2] = __float_as_uint(c1 * 1.4142135f);
        tab[k][3] = __float_as_uint(e);
        tab[k][4] = x0;
        tab[k][5] = x1;
        tab[k][6] = x0 ^ x1 ^ 0x1BD11BDAu;
        tab[k][7] = 0u;
    }
    __syncthreads();
    const int j  = (int)(blockIdx.x * 256u + threadIdx.x);
    const int ns = j / HW;
    const int hw = j - ns * HW;
    const int n  = ns >> 3;
    const int ss = ns & 7;
    const float* sk = skes + (size_t)((n * 3) * 8 + ss) * HW + hw;
    const float w0 = wskes[0], w1 = wskes[1], w2 = wskes[2];
    const float cond = fmaf(w2, sk[2 * 8 * HW], fmaf(w1, sk[8 * HW], w0 * sk[0]));
    const float sT = silT[j];
    float sil = sT;
    float* op = out + j;
#pragma unroll 2
    for (int k = 0; k < NSTEP; ++k) {
        const uint4 ta = *(const uint4*)&tab[k][0];
        const uint4 tb = *(const uint4*)&tab[k][4];
        uint32_t x0 = 0u, x1 = (uint32_t)j;
        tf20(tb.x, tb.y, tb.z, x0, x1);
        const float ei = bits_to_erfinv(x0 ^ x1);
        const float d  = fmaf(__uint_as_float(ta.z), ei, __uint_as_float(ta.w) * sT);
        const float s0 = fast_tanh(fmaf(wsil, sil, cond) + __uint_as_float(ta.y));
        *op = s0; op += NELEM;
        sil = fmaf(__uint_as_float(ta.x), s0, d);
    }
}

extern "C" void kernel_launch(void* const* d_in, const int* in_sizes, int n_in,
                              void* d_out, int out_size, void* d_ws, size_t ws_size,
                              hipStream_t stream) {
    const float* skes = (const float*)d_in[0];
    const float* silT = (const float*)d_in[1];
    const float* wsk  = (const float*)d_in[2];
    const float* wsil = (const float*)d_in[3];
    const float* tsc  = (const float*)d_in[4];
    float* out = (float*)d_out;
    (void)in_sizes; (void)n_in; (void)out_size;

    if (ws_size >= (size_t)WS_NEED) {
        uint4* tabPg = (uint4*)d_ws;
        uint2* tabCg = (uint2*)((char*)d_ws + TABC_OFF);
        hipLaunchKernelGGL(setup_kernel, dim3(4), dim3(256), 0, stream,
                           tsc, tabPg, tabCg);
        dim3 grid(NELEM / EPB), block(BLK);
        hipLaunchKernelGGL(fused_kernel, grid, block, 0, stream,
                           skes, silT, wsk, wsil, tabPg, tabCg, out);
    } else {
        dim3 grid(NELEM / 256), block(256);
        hipLaunchKernelGGL(diffgait_mono, grid, block, 0, stream,
                           skes, silT, wsk, wsil, tsc, out);
    }
}

// Round 11
// 308.426 us; speedup vs baseline: 1.2000x; 1.2000x over previous
//
#include <hip/hip_runtime.h>
#include <cstdint>

#define NSTEP 1000
#define NELEM 45056          // 704 groups of 64
#define HW    2816           // 64 * 44
#define WPG   5              // waves per group (block) sharing 64 elements
#define WIN   20             // k-steps per window; NSTEP % (WIN*WPG) == 0
#define NWIN  (NSTEP / WIN)  // 50
#define SPW   (NWIN / WPG)   // 10 scan-windows per wave
#define BLK   (WPG * 64)     // 320 threads
#define TABC_OFF 16384       // byte offset of tabC in workspace
#define WS_NEED  (TABC_OFF + NSTEP * 8)

// ---------- compile-time fp64 DDIM schedule (bit-exact vs np.linspace+cumprod) ----------
struct AlphTab { float a[NSTEP + 1]; };

constexpr AlphTab make_alph() {
    AlphTab t{};
    t.a[0] = 1.0f;
    double alph = 1.0;
    const double start = 1e-4, stop = 0.02;
    const double step = (stop - start) / 999.0;
    for (int i = 0; i < NSTEP; ++i) {
        double beta = (i == NSTEP - 1) ? stop : ((double)i * step + start);
        alph *= (1.0 - beta);
        t.a[i + 1] = (float)alph;
    }
    return t;
}
constexpr AlphTab ALPH = make_alph();

// ---------- Threefry-2x32-20 (partitionable-mode usage: ctr=(0,j), out = x0^x1) ----------
__device__ __forceinline__ void tf20(uint32_t K0, uint32_t K1, uint32_t K2,
                                     uint32_t& x0, uint32_t& x1) {
    x0 += K0; x1 += K1;
#define TFR(r) { x0 += x1; x1 = ((x1 << r) | (x1 >> (32 - r))); x1 ^= x0; }
    TFR(13) TFR(15) TFR(26) TFR(6)
    x0 += K1; x1 += K2 + 1u;
    TFR(17) TFR(29) TFR(16) TFR(24)
    x0 += K2; x1 += K0 + 2u;
    TFR(13) TFR(15) TFR(26) TFR(6)
    x0 += K0; x1 += K1 + 3u;
    TFR(17) TFR(29) TFR(16) TFR(24)
    x0 += K1; x1 += K2 + 4u;
    TFR(13) TFR(15) TFR(26) TFR(6)
    x0 += K2; x1 += K0 + 5u;
#undef TFR
}

__device__ __forceinline__ float fast_tanh(float x) {
    const float e2 = __expf(x + x);
    const float r  = __builtin_amdgcn_rcpf(e2 + 1.0f);
    return fmaf(-2.0f, r, 1.0f);
}

// bits -> erfinv(u). Dual-poly, single select; wave-uniform skip of the far
// branch (P(any of 64 lanes far) ~ 19%). Bit-identical to the reference poly.
__device__ __forceinline__ float bits_to_erfinv(uint32_t bits) {
    const float f2 = __uint_as_float((bits >> 9) | 0x3F800000u) - 1.0f;
    const float u  = f2 * 2.0f - 0.99999994f;
    const float t1 = (1.0f - u) * (1.0f + u);
    const float w  = __log2f(t1) * -0.6931472f;
    const bool  lt = w < 5.0f;

    const float wwn = w - 2.5f;
    float pn =           2.81022636e-08f;
    pn = fmaf(pn, wwn,   3.43273939e-07f);
    pn = fmaf(pn, wwn,  -3.5233877e-06f);
    pn = fmaf(pn, wwn,  -4.39150654e-06f);
    pn = fmaf(pn, wwn,   0.00021858087f);
    pn = fmaf(pn, wwn,  -0.00125372503f);
    pn = fmaf(pn, wwn,  -0.00417768164f);
    pn = fmaf(pn, wwn,   0.246640727f);
    pn = fmaf(pn, wwn,   1.50140941f);

    float p = pn;
    if (__any(!lt)) {                                 // wave-uniform branch
        const float sw  = __builtin_amdgcn_sqrtf(w);  // w >= 0 always
        const float wwf = sw - 3.0f;
        float pf =           -0.000200214257f;
        pf = fmaf(pf, wwf,    0.000100950558f);
        pf = fmaf(pf, wwf,    0.00134934322f);
        pf = fmaf(pf, wwf,   -0.00367342844f);
        pf = fmaf(pf, wwf,    0.00573950773f);
        pf = fmaf(pf, wwf,   -0.0076224613f);
        pf = fmaf(pf, wwf,    0.00943887047f);
        pf = fmaf(pf, wwf,    1.00167406f);
        pf = fmaf(pf, wwf,    2.83297682f);
        p = lt ? pn : pf;
    }
    return p * u;
}

// =====================================================================
// Setup kernel: DDIM schedule + per-step threefry keys -> GLOBAL memory.
// =====================================================================
__global__ __launch_bounds__(256)
void setup_kernel(const float* __restrict__ tsc_p,
                  uint4* __restrict__ tabPg, uint2* __restrict__ tabCg) {
    const int k = (int)(blockIdx.x * 256u + threadIdx.x);
    if (k >= NSTEP) return;
    const float tsc = tsc_p[0];
    const float L2E2 = 2.8853900817779268f;      // 2*log2(e)
    const int t = 999 - k;
    const float at  = ALPH.a[t + 1];
    const float atn = ALPH.a[t];
    const float c1 = 0.1f * sqrtf((1.0f - at / atn) * (1.0f - atn) / (1.0f - at));
    const float c2 = sqrtf(fmaxf(1.0f - atn - c1 * c1, 0.0f));
    const float rs = 1.0f / sqrtf(1.0f - at);
    const float A  = sqrtf(atn) - c2 * sqrtf(at) * rs;
    const float e  = c2 * rs;
    const float temb = tsc * ((float)t / 1000.0f);
    // fold_in(key(42), t): key <- threefry(key=[0,42], ctr=[0,t])
    uint32_t k0 = 0u, k1 = (uint32_t)t;
    tf20(0u, 42u, 0x1BD11BDAu ^ 42u, k0, k1);
    tabPg[k] = make_uint4(__float_as_uint(c1 * 1.4142135f),
                          __float_as_uint(e), k0, k1);
    tabCg[k] = make_uint2(__float_as_uint(A), __float_as_uint(temb * L2E2));
}

// =====================================================================
// ALL-PRODUCER WAVE ROTATION kernel (resubmission of r10; infra failure).
//   grid = 704 blocks x 320 threads (5 waves). Block = one group of 64
//   elements; ALL 5 waves generate noise (registers, WIN=20 floats) for
//   their own scan windows, and take turns running the serial DDIM scan.
//   Wave i scans windows w === i (mod 5); before its turn it has 4 full
//   window-periods to generate. Handoff = 64-float sil + 1 monotonic
//   LDS flag (in-order DS pipe + compiler barriers; protocol from r6/r7).
//   vs r8: deletes consumer waves, dbuf LDS round-trip, and ALL main-loop
//   __syncthreads -- targets r0-rng's 74% barrier-free issue efficiency.
// Deadlock audit: flags published strictly in order 1..NWIN by the wave
// owning the preceding window; all 5 waves co-resident (one workgroup);
// no cross-block dependency; spin is s_sleep-padded and bounded by
// producer progress. LDS: sil 256B + flag.
// =====================================================================
__global__ __launch_bounds__(BLK)
void fused_kernel(const float* __restrict__ skes,
                  const float* __restrict__ silT,
                  const float* __restrict__ wskes,
                  const float* __restrict__ wsil_p,
                  const uint4* __restrict__ tabPg,
                  const uint2* __restrict__ tabCg,
                  float* __restrict__ out) {
    __shared__ float    lds_sil[64];
    __shared__ uint32_t flag;          // next window to be scanned

    const int wid  = (int)(threadIdx.x >> 6);
    const int lane = (int)(threadIdx.x & 63);
    const int j    = (int)(blockIdx.x * 64u) + lane;

    if (threadIdx.x == 0) flag = 0u;

    // per-lane state (every wave owns the same 64 elements)
    const float L2E2 = 2.8853900817779268f;
    const float sT = silT[j];
    const int ns = j / HW;
    const int hw = j - ns * HW;
    const int n  = ns >> 3;
    const int ss = ns & 7;
    const float* sk = skes + (size_t)((n * 3) * 8 + ss) * HW + hw;
    const float w0 = wskes[0], w1 = wskes[1], w2 = wskes[2];
    const float cond = fmaf(w2, sk[2 * 8 * HW], fmaf(w1, sk[8 * HW], w0 * sk[0]));
    const float cc2 = cond * L2E2;
    const float ws2 = wsil_p[0] * L2E2;

    __syncthreads();   // flag init visible; the ONLY barrier.

    volatile uint32_t* vflag = &flag;
    float* op = out + j;

#pragma unroll 1
    for (int s = 0; s < SPW; ++s) {
        const int w  = s * WPG + wid;      // this wave's next scan window
        const int kb = w * WIN;
        const int ks0 = __builtin_amdgcn_readfirstlane(kb);

        // ---- generate this window's noise into registers (no LDS) ----
        float nz[WIN];
#pragma unroll
        for (int kk = 0; kk < WIN; ++kk) {
            const uint4 ta = tabPg[ks0 + kk];          // wave-uniform s_load
            uint32_t x0 = 0u, x1 = (uint32_t)j;        // partitionable ctr (0, j)
            tf20(ta.z, ta.w, ta.z ^ ta.w ^ 0x1BD11BDAu, x0, x1);
            const float ei = bits_to_erfinv(x0 ^ x1);
            nz[kk] = fmaf(__uint_as_float(ta.x), ei, __uint_as_float(ta.y) * sT);
        }

        // ---- wait for the ring to reach this window ----
        while (*vflag < (uint32_t)w) __builtin_amdgcn_s_sleep(1);
        asm volatile("" ::: "memory");
        float sil = (w == 0) ? sT : lds_sil[lane];

        // ---- serial scan over this window (scheduler-prioritized) ----
        __builtin_amdgcn_s_setprio(1);
        float* opw = op + (size_t)kb * NELEM;
#pragma unroll
        for (int kk = 0; kk < WIN; ++kk) {
            const uint2 tt = tabCg[ks0 + kk];          // wave-uniform s_load
            const float A  = __uint_as_float(tt.x);
            const float tb = __uint_as_float(tt.y);
            const float e2 = __builtin_amdgcn_exp2f(fmaf(ws2, sil, cc2 + tb));
            const float r  = __builtin_amdgcn_rcpf(e2 + 1.0f);
            const float s0 = fmaf(-2.0f, r, 1.0f);
            opw[(size_t)kk * NELEM] = s0;
            sil = fmaf(A, s0, nz[kk]);
        }
        __builtin_amdgcn_s_setprio(0);

        // ---- publish sil + advance ring (in-order DS pipe) ----
        lds_sil[lane] = sil;
        asm volatile("" ::: "memory");
        *vflag = (uint32_t)(w + 1);        // all lanes, same addr/value
        asm volatile("" ::: "memory");
    }
}

// =====================================================================
// Fallback: monolithic kernel (only if ws_size too small). r0 semantics.
// =====================================================================
__global__ __launch_bounds__(256)
void diffgait_mono(const float* __restrict__ skes,
                   const float* __restrict__ silT,
                   const float* __restrict__ wskes,
                   const float* __restrict__ wsil_p,
                   const float* __restrict__ tsc_p,
                   float* __restrict__ out) {
    __shared__ __align__(16) uint32_t tab[NSTEP][8];
    const float wsil = wsil_p[0];
    const float tsc  = tsc_p[0];
    for (int k = (int)threadIdx.x; k < NSTEP; k += 256) {
        const int t = 999 - k;
        const float at  = ALPH.a[t + 1];
        const float atn = ALPH.a[t];
        const float c1 = 0.1f * sqrtf((1.0f - at / atn) * (1.0f - atn) / (1.0f - at));
        const float c2 = sqrtf(fmaxf(1.0f - atn - c1 * c1, 0.0f));
        const float rs = 1.0f / sqrtf(1.0f - at);
        const float A  = sqrtf(atn) - c2 * sqrtf(at) * rs;
        const float e  = c2 * rs;
        const float temb = tsc * ((float)t / 1000.0f);
        uint32_t x0 = 0u, x1 = (uint32_t)t;
        tf20(0u, 42u, 0x1BD11BDAu ^ 42u, x0, x1);
        tab[k][0] = __float_as_uint(A);
        tab[k][1] = __float_as_uint(temb);
        tab[k][2] = __float_as_uint(c1 * 1.4142135f);
        tab[k][3] = __float_as_uint(e);
        tab[k][4] = x0;
        tab[k][5] = x1;
        tab[k][6] = x0 ^ x1 ^ 0x1BD11BDAu;
        tab[k][7] = 0u;
    }
    __syncthreads();
    const int j  = (int)(blockIdx.x * 256u + threadIdx.x);
    const int ns = j / HW;
    const int hw = j - ns * HW;
    const int n  = ns >> 3;
    const int ss = ns & 7;
    const float* sk = skes + (size_t)((n * 3) * 8 + ss) * HW + hw;
    const float w0 = wskes[0], w1 = wskes[1], w2 = wskes[2];
    const float cond = fmaf(w2, sk[2 * 8 * HW], fmaf(w1, sk[8 * HW], w0 * sk[0]));
    const float sT = silT[j];
    float sil = sT;
    float* op = out + j;
#pragma unroll 2
    for (int k = 0; k < NSTEP; ++k) {
        const uint4 ta = *(const uint4*)&tab[k][0];
        const uint4 tb = *(const uint4*)&tab[k][4];
        uint32_t x0 = 0u, x1 = (uint32_t)j;
        tf20(tb.x, tb.y, tb.z, x0, x1);
        const float ei = bits_to_erfinv(x0 ^ x1);
        const float d  = fmaf(__uint_as_float(ta.z), ei, __uint_as_float(ta.w) * sT);
        const float s0 = fast_tanh(fmaf(wsil, sil, cond) + __uint_as_float(ta.y));
        *op = s0; op += NELEM;
        sil = fmaf(__uint_as_float(ta.x), s0, d);
    }
}

extern "C" void kernel_launch(void* const* d_in, const int* in_sizes, int n_in,
                              void* d_out, int out_size, void* d_ws, size_t ws_size,
                              hipStream_t stream) {
    const float* skes = (const float*)d_in[0];
    const float* silT = (const float*)d_in[1];
    const float* wsk  = (const float*)d_in[2];
    const float* wsil = (const float*)d_in[3];
    const float* tsc  = (const float*)d_in[4];
    float* out = (float*)d_out;
    (void)in_sizes; (void)n_in; (void)out_size;

    if (ws_size >= (size_t)WS_NEED) {
        uint4* tabPg = (uint4*)d_ws;
        uint2* tabCg = (uint2*)((char*)d_ws + TABC_OFF);
        hipLaunchKernelGGL(setup_kernel, dim3(4), dim3(256), 0, stream,
                           tsc, tabPg, tabCg);
        dim3 grid(NELEM / 64), block(BLK);
        hipLaunchKernelGGL(fused_kernel, grid, block, 0, stream,
                           skes, silT, wsk, wsil, tabPg, tabCg, out);
    } else {
        dim3 grid(NELEM / 256), block(256);
        hipLaunchKernelGGL(diffgait_mono, grid, block, 0, stream,
                           skes, silT, wsk, wsil, tsc, out);
    }
}